// Round 17
// baseline (1890.929 us; speedup 1.0000x reference)
//
#include <hip/hip_runtime.h>
#include <hip/hip_cooperative_groups.h>
#include <hip/hip_fp16.h>
#include <math.h>

#define N_ 4
#define C_ 31
#define H_ 128
#define W_ 128
#define TOTAL (N_*C_*H_*W_)
#define CV_ (C_*H_*W_)
#define PI_F 3.14159265358979f
#define RHO_F 1.05f
#define INV_RHO (1.0f/1.05f)
#define NORM2 (1.0f/16384.0f)    // 1/(128*128)

typedef __attribute__((ext_vector_type(2))) float v2f;
typedef __attribute__((ext_vector_type(2))) _Float16 h2f;

__device__ __forceinline__ v2f cmulv(v2f a, v2f b){
  v2f t = a.x * b;
  v2f s = (v2f){-a.y, a.y};
  return t + s * b.yx;
}
__device__ __forceinline__ v2f shflv(v2f v, int m){
  v2f r; r.x = __shfl_xor(v.x, m, 64); r.y = __shfl_xor(v.y, m, 64); return r;
}
__device__ __forceinline__ h2f shflh(h2f v, int m){
  float f = __builtin_bit_cast(float, v);
  f = __shfl_xor(f, m, 64);
  return __builtin_bit_cast(h2f, f);
}
__device__ __forceinline__ float shrinkf(float x, float t){
  return copysignf(fmaxf(fabsf(x) - t, 0.0f), x);
}
__device__ __forceinline__ uint packh2(v2f v){
  union{__half2 h2; uint u;} cv; cv.h2 = __floats2half2_rn(v.x, v.y); return cv.u;
}
__device__ __forceinline__ v2f unpackh2(uint u){
  union{uint uu; __half2 h2;} cv; cv.uu = u;
  float2 f = __half22float2(cv.h2);
  return (v2f){f.x, f.y};
}
__device__ __forceinline__ v2f h2v(__half2 h){
  float2 f = __half22float2(h);
  return (v2f){f.x, f.y};
}
// V recurrence: vnew = shrink((1+1/rho)*D - vold/rho, thr) + (vold - D)/rho
__device__ __forceinline__ v2f vupd(v2f D, v2f vo, float thr){
  const float aa = 1.0f + INV_RHO;
  return (v2f){
    shrinkf(aa*D.x - vo.x*INV_RHO, thr) + (vo.x - D.x)*INV_RHO,
    shrinkf(aa*D.y - vo.y*INV_RHO, thr) + (vo.y - D.y)*INV_RHO};
}
__device__ __forceinline__ void load_tw(const v2f* __restrict__ lut, v2f* tw, int lane){
  #pragma unroll
  for (int i = 0; i < 7; ++i) tw[i] = lut[i*64 + lane];
}

// Forward DIF FFT-128 (fp32); outputs bit-reversed positions.
__device__ __forceinline__ void fft128_fwd(v2f& a, v2f& b, const v2f* twf, int t){
  v2f u = a + b;
  v2f v = cmulv(a - b, twf[0]);
  #pragma unroll
  for (int i = 1; i < 7; ++i){
    int sp = 64 >> i;
    bool up = (t & sp) != 0;
    v2f pu = shflv(u, sp);
    v2f du = up ? pu - u : u + pu;
    u = cmulv(du, twf[i]);
    v2f pv = shflv(v, sp);
    v2f dv = up ? pv - v : v + pv;
    v = cmulv(dv, twf[i]);
  }
  a = u; b = v;
}

// Inverse DIT FFT-128 (fp32, unnormalized): bit-reversed in, natural out.
__device__ __forceinline__ void fft128_inv(v2f& a, v2f& b, const v2f* twi, int t){
  v2f u = a, v = b;
  #pragma unroll
  for (int i = 6; i >= 1; --i){
    int sp = 64 >> i;
    bool up = (t & sp) != 0;
    v2f pu = shflv(u, sp);
    v2f e  = up ? pu : u;
    v2f o  = up ? u  : pu;
    v2f wo = cmulv(o, twi[i]);
    u = up ? e - wo : e + wo;
    v2f pv = shflv(v, sp);
    v2f ev = up ? pv : v;
    v2f ov = up ? v  : pv;
    v2f wv = cmulv(ov, twi[i]);
    v = up ? ev - wv : ev + wv;
  }
  v2f tv = cmulv(v, twi[0]);
  a = u + tv;
  b = u - tv;
}

// SoA dual-row inverse FFT-128 (fp16 packed): rows P(low), Q(high).
__device__ __forceinline__ void fft128_inv_h2(h2f& are, h2f& aim, h2f& bre, h2f& bim,
    const uint* __restrict__ twc, const uint* __restrict__ tws, int t){
  #pragma unroll
  for (int i = 6; i >= 1; --i){
    int sp = 64 >> i;
    bool up = (t & sp) != 0;
    h2f c2 = __builtin_bit_cast(h2f, twc[i*64 + t]);
    h2f s2 = __builtin_bit_cast(h2f, tws[i*64 + t]);
    h2f pre = shflh(are, sp), pim = shflh(aim, sp);
    h2f e_re = up ? pre : are, e_im = up ? pim : aim;
    h2f o_re = up ? are : pre, o_im = up ? aim : pim;
    are = e_re + (o_re*c2 - o_im*s2);
    aim = e_im + (o_re*s2 + o_im*c2);
    pre = shflh(bre, sp); pim = shflh(bim, sp);
    e_re = up ? pre : bre; e_im = up ? pim : bim;
    o_re = up ? bre : pre; o_im = up ? bim : pim;
    bre = e_re + (o_re*c2 - o_im*s2);
    bim = e_im + (o_re*s2 + o_im*c2);
  }
  h2f c0 = __builtin_bit_cast(h2f, twc[t]);
  h2f s0 = __builtin_bit_cast(h2f, tws[t]);
  h2f tr = bre*c0 - bim*s0;
  h2f ti = bre*s0 + bim*c0;
  h2f ur = are, ui = aim;
  are = ur + tr; aim = ui + ti;
  bre = ur - tr; bim = ui - ti;
}

// SoA dual-row FORWARD DIF FFT-128 (fp16 packed).
__device__ __forceinline__ void fft128_fwd_h2(h2f& are, h2f& aim, h2f& bre, h2f& bim,
    const uint* __restrict__ twc, const uint* __restrict__ tws, int t){
  h2f c0 = __builtin_bit_cast(h2f, twc[t]);
  h2f s0 = __builtin_bit_cast(h2f, tws[t]);
  h2f dre = are - bre, dim = aim - bim;
  h2f ure = are + bre, uim = aim + bim;
  h2f vre = dre*c0 - dim*s0;
  h2f vim = dre*s0 + dim*c0;
  #pragma unroll
  for (int i = 1; i < 7; ++i){
    int sp = 64 >> i;
    bool up = (t & sp) != 0;
    h2f c2 = __builtin_bit_cast(h2f, twc[i*64 + t]);
    h2f s2 = __builtin_bit_cast(h2f, tws[i*64 + t]);
    h2f sg = up ? (h2f){(_Float16)-1.0f, (_Float16)-1.0f} : (h2f){(_Float16)1.0f, (_Float16)1.0f};
    h2f pre = shflh(ure, sp), pim = shflh(uim, sp);
    h2f d1 = sg*ure + pre, d2 = sg*uim + pim;
    ure = d1*c2 - d2*s2; uim = d1*s2 + d2*c2;
    pre = shflh(vre, sp); pim = shflh(vim, sp);
    d1 = sg*vre + pre; d2 = sg*vim + pim;
    vre = d1*c2 - d2*s2; vim = d1*s2 + d2*c2;
  }
  are = ure; aim = uim; bre = vre; bim = vim;
}

// K-1: one-time twiddle/demo LUT init. 1 block, 128 threads.
__global__ __launch_bounds__(128) void kern_init(v2f* __restrict__ twf_lut,
    v2f* __restrict__ twi_lut, float* __restrict__ dtab,
    uint* __restrict__ twihc, uint* __restrict__ twihs,
    uint* __restrict__ twfhc, uint* __restrict__ twfhs)
{
  int t = threadIdx.x;
  if (t < 64){
    float s, c;
    sincosf(-2.0f*PI_F*(float)t/128.0f, &s, &c);
    twf_lut[t] = (v2f){c, s};
    { union{__half2 h; uint u;} cc, ss;
      cc.h = __floats2half2_rn(c, c); ss.h = __floats2half2_rn(s, s);
      twfhc[t] = cc.u; twfhs[t] = ss.u; }
    sincosf(+2.0f*PI_F*(float)t/128.0f, &s, &c);
    twi_lut[t] = (v2f){c, s};
    { union{__half2 h; uint u;} cc, ss;
      cc.h = __floats2half2_rn(c, c); ss.h = __floats2half2_rn(s, s);
      twihc[t] = cc.u; twihs[t] = ss.u; }
    #pragma unroll
    for (int i = 1; i < 7; ++i){
      int sp = 64 >> i;
      float angf = (t & sp) ? -2.0f*PI_F*(float)(t&(sp-1))/(float)(2*sp) : 0.0f;
      sincosf(angf, &s, &c);
      twf_lut[i*64 + t] = (v2f){c, s};
      { union{__half2 h; uint u;} cc, ss;
        cc.h = __floats2half2_rn(c, c); ss.h = __floats2half2_rn(s, s);
        twfhc[i*64 + t] = cc.u; twfhs[i*64 + t] = ss.u; }
      float angi = +2.0f*PI_F*(float)(t&(sp-1))/(float)(2*sp);
      sincosf(angi, &s, &c);
      twi_lut[i*64 + t] = (v2f){c, s};
      float ch = c, sh = s;
      if (t & sp){ ch = -ch; sh = -sh; }
      union{__half2 h; uint u;} cc, ss;
      cc.h = __floats2half2_rn(ch, ch); ss.h = __floats2half2_rn(sh, sh);
      twihc[i*64 + t] = cc.u; twihs[i*64 + t] = ss.u;
    }
  }
  dtab[t] = 2.0f - 2.0f*cosf(2.0f*PI_F*(float)t/128.0f);
}

// K0: one-time pack
__global__ __launch_bounds__(256) void kern_pack(const float* __restrict__ Y,
    const float* __restrict__ W, uint2* __restrict__ YWp)
{
  int i = blockIdx.x * 256 + threadIdx.x;
  int pair = i / CV_, j = i - pair*CV_;
  long b0 = (long)(2*pair)*CV_ + j, b1 = b0 + CV_;
  union{__half2 h2; uint u;} a, b;
  a.h2 = __floats2half2_rn(Y[b0], W[b0]);
  b.h2 = __floats2half2_rn(Y[b1], W[b1]);
  YWp[i] = make_uint2(a.u, b.u);
}

// K1: first iteration.
__global__ __launch_bounds__(256) void kern_fwd0(const float* __restrict__ Y,
    __half2* __restrict__ Vho, __half2* __restrict__ Vvo, __half2* __restrict__ Vso,
    __half2* __restrict__ A, float thr, const v2f* __restrict__ twf_lut)
{
  __shared__ v2f  zbuf[26][128];
  __shared__ uint zs[25][128];
  int tid = threadIdx.x, lane = tid & 63, wv = tid >> 6;
  int b = blockIdx.x;
  int ht = b & 15, c = (b >> 4) % C_, pair = b / (16*C_);
  int h0 = ht * 8;
  int cm1 = c ? c-1 : C_-1, cp1 = (c == C_-1) ? 0 : c+1;
  long v0 = (long)(2*pair)*CV_, v1 = v0 + CV_;

  for (int u = wv; u < 26; u += 4){
    int cc, h;
    if (u < 10){ cc = c; h = (h0 - 1 + u) & (H_-1); }
    else if (u < 18){ cc = cm1; h = h0 + u - 10; }
    else { cc = cp1; h = h0 + u - 18; }
    long rb = ((long)cc*H_ + h)*W_;
    #pragma unroll
    for (int e = 0; e < 2; ++e){
      int w = lane + 64*e;
      zbuf[u][w] = (v2f){Y[v0+rb+w], Y[v1+rb+w]};
    }
  }
  __syncthreads();

  v2f q[2][2], vs[2][2], vsm[2][2];
  #pragma unroll
  for (int r = 0; r < 2; ++r){
    int i = wv + 4*r, h = h0 + i;
    long pv = ((long)(pair*C_ + c)*H_ + h)*W_;
    #pragma unroll
    for (int e = 0; e < 2; ++e){
      int w = lane + 64*e;
      v2f z0 = zbuf[i+1][w];
      v2f zw = zbuf[i+1][(w+1)&(W_-1)];
      v2f zh = zbuf[i+2][w];
      v2f zc = zbuf[18+i][w];
      v2f zm = zbuf[10+i][w];
      v2f vh = (v2f){shrinkf(z0.x-zw.x,thr), shrinkf(z0.y-zw.y,thr)};
      v2f vv = (v2f){shrinkf(z0.x-zh.x,thr), shrinkf(z0.y-zh.y,thr)};
      v2f vsl= (v2f){shrinkf(z0.x-zc.x,thr), shrinkf(z0.y-zc.y,thr)};
      vsm[r][e] = (v2f){shrinkf(zm.x-z0.x,thr), shrinkf(zm.y-z0.y,thr)};
      Vho[pv+w] = __floats2half2_rn(vh.x, vh.y);
      Vvo[pv+w] = __floats2half2_rn(vv.x, vv.y);
      Vso[pv+w] = __floats2half2_rn(vsl.x, vsl.y);
      zs[i][w]   = packh2(vh);
      zs[9+i][w] = packh2(vv);
      vs[r][e] = vsl;
      q[r][e]  = z0;
    }
  }
  if (wv == 0){
    #pragma unroll
    for (int e = 0; e < 2; ++e){
      int w = lane + 64*e;
      v2f z0 = zbuf[0][w], zh = zbuf[1][w];
      v2f vvm = (v2f){shrinkf(z0.x-zh.x,thr), shrinkf(z0.y-zh.y,thr)};
      zs[8][w] = packh2(vvm);
    }
  }
  __syncthreads();

  v2f twf[7]; load_tw(twf_lut, twf, lane);
  #pragma unroll
  for (int r = 0; r < 2; ++r){
    int i = wv + 4*r;
    v2f nm[2];
    #pragma unroll
    for (int e = 0; e < 2; ++e){
      int w = lane + 64*e;
      v2f vh  = unpackh2(zs[i][w]);
      v2f vhm = unpackh2(zs[i][(w+W_-1)&(W_-1)]);
      v2f vv  = unpackh2(zs[9+i][w]);
      v2f vvm = unpackh2(zs[8+i][w]);
      nm[e] = q[r][e] + (vh - vhm) + (vv - vvm) + (vs[r][e] - vsm[r][e]);
    }
    fft128_fwd(nm[0], nm[1], twf, lane);
    zs[17+i][lane]    = packh2(nm[0]);
    zs[17+i][lane+64] = packh2(nm[1]);
  }
  __syncthreads();
  int4* A4 = (int4*)A;
  int p = tid >> 1, hq = tid & 1;
  union{int4 v; uint e[4];} u;
  #pragma unroll
  for (int j = 0; j < 4; ++j) u.e[j] = zs[17 + 4*hq + j][p];
  A4[((long)(pair*W_ + p)*C_ + c)*32 + 2*ht + hq] = u.v;
}

// CH phase body: H-FFT fwd (fp16 SoA) + 17-tap circulant c-solve (fp32) + H-FFT inv (fp16 SoA).
__device__ __forceinline__ void ch_body(__half2* __restrict__ A, char* smem,
    const uint* __restrict__ twfhc, const uint* __restrict__ twfhs,
    const uint* __restrict__ twihc, const uint* __restrict__ twihs,
    const float* __restrict__ dtab)
{
  v2f (*slab)[H_]  = (v2f(*)[H_])(smem);
  v2f (*slab2)[H_] = (v2f(*)[H_])(smem + 31744);
  int tid = threadIdx.x, lane = tid & 63, wv = tid >> 6;
  int bid = blockIdx.x;                 // pair*128 + w
  int w = bid & (W_-1);
  const int4* g4 = (const int4*)(A + (long)bid * C_ * H_);

  if (tid < 992){
    union { int4 v; __half2 e[4]; } u;
    u.v = g4[tid];
    int c = tid >> 5, hb = (tid & 31) << 2;
    #pragma unroll
    for (int j = 0; j < 4; ++j) slab[c][hb+j] = h2v(u.e[j]);
  }
  __syncthreads();

  {
    int c1 = wv, c2 = (wv + 16 < C_) ? wv + 16 : (C_-1);
    v2f a0 = slab[c1][lane], b0 = slab[c1][lane+64];
    v2f a1 = slab[c2][lane], b1 = slab[c2][lane+64];
    h2f are = (h2f){(_Float16)a0.x, (_Float16)a1.x};
    h2f aim = (h2f){(_Float16)a0.y, (_Float16)a1.y};
    h2f bre = (h2f){(_Float16)b0.x, (_Float16)b1.x};
    h2f bim = (h2f){(_Float16)b0.y, (_Float16)b1.y};
    fft128_fwd_h2(are, aim, bre, bim, twfhc, twfhs, lane);
    slab[c1][lane]    = (v2f){(float)are.x, (float)aim.x};
    slab[c1][lane+64] = (v2f){(float)bre.x, (float)bim.x};
    if (wv + 16 < C_){
      slab[c2][lane]    = (v2f){(float)are.y, (float)aim.y};
      slab[c2][lane+64] = (v2f){(float)bre.y, (float)bim.y};
    }
  }
  __syncthreads();

  {
    int col = tid & (H_-1), cb = tid >> 7, c0 = cb * 4;
    int fh = __brev(col) >> 25;
    int fw = __brev(w)   >> 25;
    float beta = 1.0f + dtab[fh] + dtab[fw];
    float a2 = beta + 2.0f;
    float s  = sqrtf(a2*a2 - 4.0f);
    float rg = (a2 - s) * 0.5f;
    float gt[9];
    gt[0] = NORM2 / s;
    #pragma unroll
    for (int t = 1; t < 9; ++t) gt[t] = gt[t-1] * rg;

    v2f win[20];
    #pragma unroll
    for (int i = 0; i < 20; ++i){
      int ci = c0 - 8 + i;
      if (ci < 0) ci += C_;
      if (ci >= C_) ci -= C_;
      win[i] = slab[ci][col];
    }
    #pragma unroll
    for (int j = 0; j < 4; ++j){
      v2f o = (v2f){0.0f, 0.0f};
      #pragma unroll
      for (int t = -8; t <= 8; ++t){
        float gv = gt[t < 0 ? -t : t];
        o += gv * win[j + 8 - t];
      }
      int c = c0 + j;
      if (c < C_) slab2[c][col] = o;
    }
  }
  __syncthreads();

  {
    int c1 = wv, c2 = (wv + 16 < C_) ? wv + 16 : (C_-1);
    v2f a0 = slab2[c1][lane], b0 = slab2[c1][lane+64];
    v2f a1 = slab2[c2][lane], b1 = slab2[c2][lane+64];
    h2f are = (h2f){(_Float16)a0.x, (_Float16)a1.x};
    h2f aim = (h2f){(_Float16)a0.y, (_Float16)a1.y};
    h2f bre = (h2f){(_Float16)b0.x, (_Float16)b1.x};
    h2f bim = (h2f){(_Float16)b0.y, (_Float16)b1.y};
    fft128_inv_h2(are, aim, bre, bim, twihc, twihs, lane);
    slab2[c1][lane]    = (v2f){(float)are.x, (float)aim.x};
    slab2[c1][lane+64] = (v2f){(float)bre.x, (float)bim.x};
    if (wv + 16 < C_){
      slab2[c2][lane]    = (v2f){(float)are.y, (float)aim.y};
      slab2[c2][lane+64] = (v2f){(float)bre.y, (float)bim.y};
    }
  }
  __syncthreads();
  int4* go4 = (int4*)(A + (long)bid * C_ * H_);
  if (tid < 992){
    int c = tid >> 5, hb = (tid & 31) << 2;
    union { int4 v; __half2 e[4]; } u;
    #pragma unroll
    for (int j = 0; j < 4; ++j){
      v2f f = slab2[c][hb+j];
      u.e[j] = __floats2half2_rn(f.x, f.y);
    }
    go4[tid] = u.v;
  }
}

// CA phase body: fused iteration tail+head, 4c x 8h tiles, 1024 thr.
__device__ __forceinline__ void ca_body(
    const __half2* __restrict__ Ain, __half2* __restrict__ Aout,
    const __half2* __restrict__ Vhi, const __half2* __restrict__ Vvi, const __half2* __restrict__ Vsi,
    __half2* __restrict__ Vho, __half2* __restrict__ Vvo, __half2* __restrict__ Vso,
    const uint2* __restrict__ YWp, __half2* __restrict__ G1,
    float mu, float thrn, float invmun, int firstG, char* smem,
    const uint* __restrict__ twfhc, const uint* __restrict__ twfhs,
    const uint* __restrict__ twihc, const uint* __restrict__ twihs)
{
  v2f  (*zbuf)[128] = (v2f(*)[128])(smem);          // 56 rows fp32 = 57344 B
  uint (*zs)[128]   = (uint(*)[128])(smem + 57344); // 80 rows uint = 40960 B
  int tid = threadIdx.x, lane = tid & 63, wv = tid >> 6;   // wv 0..15
  int b = blockIdx.x;
  int ht = b & 15, ct = (b >> 4) & 7, pair = b >> 7;
  int c0 = 4*ct, nc = (ct == 7) ? 3 : 4;
  int h0 = ht * 8;
  int k = wv >> 3, hl = wv & 7;
  int cm1 = c0 ? c0-1 : C_-1;
  int cp4 = (c0 + 4) % C_;

  int cA = c0 + 2*k;
  int cB = (c0 + 2*k + 1) % C_;
  int cAm1 = cA ? cA-1 : C_-1;
  int h = h0 + hl;
  long pvA = ((long)(pair*C_ + cA)*H_ + h)*W_;
  long pvB = ((long)(pair*C_ + cB)*H_ + h)*W_;
  long pvM = ((long)(pair*C_ + cAm1)*H_ + h)*W_;
  uint pf_vh[2][2], pf_vv[2][2], pf_vs[2][2], pf_vsmA[2], pf_g1[2][2], pf_vvh[2];
  uint2 pf_yw[2][2];
  #pragma unroll
  for (int e = 0; e < 2; ++e){
    int w = lane + 64*e;
    pf_vh[0][e] = *(const uint*)(Vhi + pvA + w);
    pf_vh[1][e] = *(const uint*)(Vhi + pvB + w);
    pf_vv[0][e] = *(const uint*)(Vvi + pvA + w);
    pf_vv[1][e] = *(const uint*)(Vvi + pvB + w);
    pf_vs[0][e] = *(const uint*)(Vsi + pvA + w);
    pf_vs[1][e] = *(const uint*)(Vsi + pvB + w);
    pf_vsmA[e]  = *(const uint*)(Vsi + pvM + w);
    pf_yw[0][e] = YWp[pvA + w];
    pf_yw[1][e] = YWp[pvB + w];
    pf_g1[0][e] = *(const uint*)(G1 + pvA + w);
    pf_g1[1][e] = *(const uint*)(G1 + pvB + w);
  }
  if (wv < 4){
    int cc = (c0 + wv) % C_;
    long pvh = ((long)(pair*C_ + cc)*H_ + ((h0+H_-1)&(H_-1)))*W_;
    #pragma unroll
    for (int e = 0; e < 2; ++e){
      int w = lane + 64*e;
      pf_vvh[e] = *(const uint*)(Vvi + pvh + w);
    }
  }

  // phase 0: stage 20 quads (16 own-window + 4 c-halo) = 2560 int4.
  const int4* A4 = (const int4*)Ain;
  #pragma unroll
  for (int kk = 0; kk < 3; ++kk){
    int s = tid + 1024*kk;
    if (s < 2560){
      int qq = s >> 7, w = s & 127;
      int cc, hq, base;
      if (qq < 16){
        cc = (c0 + (qq >> 2)) % C_;
        hq = (2*ht - 1 + (qq & 3)) & 31;
        base = (qq >> 2)*16 + (qq & 3)*4;
      } else if (qq < 18){
        cc = cm1; hq = 2*ht + (qq - 16); base = 64 + (qq - 16)*4;
      } else {
        cc = cp4; hq = 2*ht + (qq - 18); base = 72 + (qq - 18)*4;
      }
      union{int4 v; uint e[4];} u;
      u.v = A4[((long)(pair*W_ + w)*C_ + cc)*32 + hq];
      #pragma unroll
      for (int j = 0; j < 4; ++j) zs[base+j][w] = u.e[j];
    }
  }
  __syncthreads();

  // phase 1: iFFT 56 zbuf rows = 28 SoA units; wave does unit wv and (wv<12) 16+wv.
  {
    #pragma unroll
    for (int kk = 0; kk < 2; ++kk){
      int j = wv + 16*kk;
      if (kk == 1 && j >= 28) break;
      int bP = 2*j, bQ = 2*j + 1;
      int zrP = (bP < 40) ? ((bP/10)*16 + (bP%10) + 3) : (bP + 24);
      int zrQ = (bQ < 40) ? ((bQ/10)*16 + (bQ%10) + 3) : (bQ + 24);
      uint r0a = zs[zrP][lane],    r1a = zs[zrQ][lane];
      uint r0b = zs[zrP][lane+64], r1b = zs[zrQ][lane+64];
      h2f are = __builtin_bit_cast(h2f, (r0a & 0xffffu) | (r1a << 16));
      h2f aim = __builtin_bit_cast(h2f, (r0a >> 16) | (r1a & 0xffff0000u));
      h2f bre = __builtin_bit_cast(h2f, (r0b & 0xffffu) | (r1b << 16));
      h2f bim = __builtin_bit_cast(h2f, (r0b >> 16) | (r1b & 0xffff0000u));
      fft128_inv_h2(are, aim, bre, bim, twihc, twihs, lane);
      zbuf[bP][lane]    = (v2f){(float)are.x, (float)aim.x};
      zbuf[bP][lane+64] = (v2f){(float)bre.x, (float)bim.x};
      zbuf[bQ][lane]    = (v2f){(float)are.y, (float)aim.y};
      zbuf[bQ][lane+64] = (v2f){(float)bre.y, (float)bim.y};
    }
  }
  __syncthreads();

  // phase 2a: V_{t+1} for rows (cA,hl),(cB,hl); X/G1/Q.
  v2f q2[2][2], vs2[2][2], vsm2[2][2];
  #pragma unroll
  for (int s = 0; s < 2; ++s){
    int cL = 2*k + s;
    bool valid = (cL < nc);
    int zb0 = 10*cL + 1 + hl;
    int zbc = (cL < 3) ? (10*(cL+1) + 1 + hl) : (48 + hl);
    int zbm = (cL == 0) ? (40 + hl) : (10*(cL-1) + 1 + hl);
    long pv = (s == 0) ? pvA : pvB;
    #pragma unroll
    for (int e = 0; e < 2; ++e){
      int w = lane + 64*e;
      v2f z0 = zbuf[zb0][w];
      v2f zw = zbuf[zb0][(w+1)&(W_-1)];
      v2f zh = zbuf[zb0+1][w];
      v2f zc = zbuf[zbc][w];
      v2f vh  = vupd(z0 - zw, unpackh2(pf_vh[s][e]), thrn);
      v2f vv  = vupd(z0 - zh, unpackh2(pf_vv[s][e]), thrn);
      v2f vsl = vupd(z0 - zc, unpackh2(pf_vs[s][e]), thrn);
      if (s == 0){
        v2f zm = zbuf[zbm][w];
        vsm2[0][e] = vupd(zm - z0, unpackh2(pf_vsmA[e]), thrn);
        vsm2[1][e] = vsl;     // cB's (c-1) term = cA's Vs
      }
      if (valid){
        Vho[pv+w] = __floats2half2_rn(vh.x, vh.y);
        Vvo[pv+w] = __floats2half2_rn(vv.x, vv.y);
        Vso[pv+w] = __floats2half2_rn(vsl.x, vsl.y);
      }
      zs[cL*8 + hl][w]      = packh2(vh);
      zs[32 + cL*8 + hl][w] = packh2(vv);
      vs2[s][e] = vsl;
      v2f a0 = unpackh2(pf_yw[s][e].x);
      v2f a1 = unpackh2(pf_yw[s][e].y);
      v2f g1 = firstG ? (v2f){0.0f, 0.0f} : unpackh2(pf_g1[s][e]);
      float x0 = (a0.y*a0.x + mu*z0.x - g1.x) * __builtin_amdgcn_rcpf(a0.y + mu);
      float x1 = (a1.y*a1.x + mu*z0.y - g1.y) * __builtin_amdgcn_rcpf(a1.y + mu);
      float g10 = g1.x + mu*(x0 - z0.x);
      float g11 = g1.y + mu*(x1 - z0.y);
      if (valid) G1[pv+w] = __floats2half2_rn(g10, g11);
      q2[s][e] = (v2f){x0 + g10*invmun, x1 + g11*invmun};
    }
  }
  if (wv < 4){
    int zb = 10*wv;               // z(c0+wv, h0-1)
    #pragma unroll
    for (int e = 0; e < 2; ++e){
      int w = lane + 64*e;
      v2f z0 = zbuf[zb][w], zh = zbuf[zb+1][w];
      v2f vvm = vupd(z0 - zh, unpackh2(pf_vvh[e]), thrn);
      zs[64 + wv][w] = packh2(vvm);
    }
  }
  __syncthreads();

  // phase 2b: numer + forward W-FFT (2 rows as one fp16-SoA FFT); tbuf aliases zbuf.
  {
    v2f nm[2][2];
    #pragma unroll
    for (int s = 0; s < 2; ++s){
      int cL = 2*k + s;
      #pragma unroll
      for (int e = 0; e < 2; ++e){
        int w = lane + 64*e;
        v2f vh  = unpackh2(zs[cL*8 + hl][w]);
        v2f vhm = unpackh2(zs[cL*8 + hl][(w+W_-1)&(W_-1)]);
        v2f vv  = unpackh2(zs[32 + cL*8 + hl][w]);
        v2f vvm = (hl == 0) ? unpackh2(zs[64 + cL][w]) : unpackh2(zs[32 + cL*8 + hl - 1][w]);
        nm[s][e] = q2[s][e] + (vh - vhm) + (vv - vvm) + (vs2[s][e] - vsm2[s][e]);
      }
    }
    bool validB = (2*k + 1 < nc);
    if (!validB){ nm[1][0] = nm[0][0]; nm[1][1] = nm[0][1]; }
    h2f are = (h2f){(_Float16)nm[0][0].x, (_Float16)nm[1][0].x};
    h2f aim = (h2f){(_Float16)nm[0][0].y, (_Float16)nm[1][0].y};
    h2f bre = (h2f){(_Float16)nm[0][1].x, (_Float16)nm[1][1].x};
    h2f bim = (h2f){(_Float16)nm[0][1].y, (_Float16)nm[1][1].y};
    fft128_fwd_h2(are, aim, bre, bim, twfhc, twfhs, lane);
    uint a_ = __builtin_bit_cast(uint, are), ai_ = __builtin_bit_cast(uint, aim);
    uint b_ = __builtin_bit_cast(uint, bre), bi_ = __builtin_bit_cast(uint, bim);
    uint* tb = (uint*)zbuf;
    int r0 = (2*k)*8 + hl, r1 = (2*k+1)*8 + hl;
    tb[r0*128 + lane]      = (a_ & 0xffffu) | (ai_ << 16);
    tb[r0*128 + lane + 64] = (b_ & 0xffffu) | (bi_ << 16);
    if (validB){
      tb[r1*128 + lane]      = (a_ >> 16) | (ai_ & 0xffff0000u);
      tb[r1*128 + lane + 64] = (b_ >> 16) | (bi_ & 0xffff0000u);
    }
  }
  __syncthreads();

  // phase 3: store 8 own quads = 1024 int4, one per thread.
  {
    int q = tid >> 7, w = tid & 127;
    int cL = q >> 1, hq2 = q & 1;
    if (cL < nc){
      const uint* tb = (const uint*)zbuf;
      int4* Ao4 = (int4*)Aout;
      union{int4 v; uint e[4];} uo;
      #pragma unroll
      for (int j = 0; j < 4; ++j) uo.e[j] = tb[(cL*8 + 4*hq2 + j)*128 + w];
      Ao4[((long)(pair*W_ + w)*C_ + (c0+cL))*32 + 2*ht + hq2] = uo.v;
    }
  }
}

// K2+K3 persistent cooperative loop: 19 x (CH; sync; CA; sync) + final CH.
__global__ __launch_bounds__(1024) void kern_loop(
    __half2* A0, __half2* A1,
    __half2* Vh0, __half2* Vv0, __half2* Vs0,
    __half2* Vh1, __half2* Vv1, __half2* Vs1,
    const uint2* YWp, __half2* G1,
    const uint* twfhc, const uint* twfhs,
    const uint* twihc, const uint* twihs,
    const float* dtab)
{
  __shared__ __align__(16) char smem[98304];
  cooperative_groups::grid_group grid = cooperative_groups::this_grid();
  float mu = 0.1f;
  #pragma unroll 1
  for (int t = 0; t < 19; ++t){
    __half2* Acur = (t & 1) ? A1 : A0;
    __half2* Anxt = (t & 1) ? A0 : A1;
    __half2* Vhc  = (t & 1) ? Vh1 : Vh0;
    __half2* Vvc  = (t & 1) ? Vv1 : Vv0;
    __half2* Vsc  = (t & 1) ? Vs1 : Vs0;
    __half2* Vhn  = (t & 1) ? Vh0 : Vh1;
    __half2* Vvn  = (t & 1) ? Vv0 : Vv1;
    __half2* Vsn  = (t & 1) ? Vs0 : Vs1;
    ch_body(Acur, smem, twfhc, twfhs, twihc, twihs, dtab);
    grid.sync();
    float mun = mu * RHO_F;
    ca_body(Acur, Anxt, Vhc, Vvc, Vsc, Vhn, Vvn, Vsn, YWp, G1,
            mu, 0.1f/mun, 1.0f/mun, (t == 0) ? 1 : 0, smem,
            twfhc, twfhs, twihc, twihs);
    mu = mun;
    grid.sync();
  }
  ch_body(A1, smem, twfhc, twfhs, twihc, twihs, dtab);
}

// K4: final: iW-FFT own rows only -> Z fp32.
__global__ __launch_bounds__(256) void kern_last(const __half2* __restrict__ A,
    float* __restrict__ Z, const v2f* __restrict__ twi_lut)
{
  __shared__ uint zs[8][128];
  int tid = threadIdx.x, lane = tid & 63, wv = tid >> 6;
  int b = blockIdx.x;
  int ht = b & 15, c = (b >> 4) % C_, pair = b / (16*C_);
  int h0 = ht * 8;
  const int4* A4 = (const int4*)A;
  {
    int p = tid >> 1, hq = tid & 1;
    union{int4 v; uint e[4];} u;
    u.v = A4[((long)(pair*W_ + p)*C_ + c)*32 + 2*ht + hq];
    #pragma unroll
    for (int j = 0; j < 4; ++j) zs[4*hq + j][p] = u.e[j];
  }
  __syncthreads();
  v2f twi[7]; load_tw(twi_lut, twi, lane);
  long v0 = (long)(2*pair)*CV_, v1 = v0 + CV_;
  #pragma unroll
  for (int r = 0; r < 2; ++r){
    int i = wv + 4*r, h = h0 + i;
    v2f a = unpackh2(zs[i][lane]);
    v2f bb = unpackh2(zs[i][lane+64]);
    fft128_inv(a, bb, twi, lane);
    long rb = ((long)c*H_ + h)*W_;
    Z[v0+rb+lane]    = a.x;  Z[v1+rb+lane]    = a.y;
    Z[v0+rb+lane+64] = bb.x; Z[v1+rb+lane+64] = bb.y;
  }
}

extern "C" void kernel_launch(void* const* d_in, const int* in_sizes, int n_in,
                              void* d_out, int out_size, void* d_ws, size_t ws_size,
                              hipStream_t stream)
{
  const float* Y   = (const float*)d_in[0];
  const float* inW = (const float*)d_in[1];
  float* Z = (float*)d_out;

  v2f*   twf_lut = (v2f*)d_ws;
  v2f*   twi_lut = twf_lut + 7*64;
  float* dtab    = (float*)(twi_lut + 7*64);
  uint*  twihc   = (uint*)(dtab + 128);
  uint*  twihs   = twihc + 7*64;
  uint*  twfhc   = twihs + 7*64;
  uint*  twfhs   = twfhc + 7*64;
  char*  fields  = (char*)d_ws + 16384;

  const int HT = TOTAL/2;
  uint2*   YWp = (uint2*)fields;
  __half2* G1  = (__half2*)(YWp + HT);
  __half2* Vh0 = G1  + HT;
  __half2* Vv0 = Vh0 + HT;
  __half2* Vs0 = Vv0 + HT;
  __half2* Vh1 = Vs0 + HT;
  __half2* Vv1 = Vh1 + HT;
  __half2* Vs1 = Vv1 + HT;
  __half2* A0  = Vs1 + HT;
  __half2* A1  = A0  + HT;

  kern_init<<<dim3(1), dim3(128), 0, stream>>>(twf_lut, twi_lut, dtab, twihc, twihs, twfhc, twfhs);
  kern_pack<<<dim3(2*CV_/256), dim3(256), 0, stream>>>(Y, inW, YWp);
  kern_fwd0<<<dim3(2*C_*16), dim3(256), 0, stream>>>(Y, Vh0, Vv0, Vs0, A0, 1.0f, twf_lut);

  {
    void* kargs[] = {
      (void*)&A0, (void*)&A1,
      (void*)&Vh0, (void*)&Vv0, (void*)&Vs0,
      (void*)&Vh1, (void*)&Vv1, (void*)&Vs1,
      (void*)&YWp, (void*)&G1,
      (void*)&twfhc, (void*)&twfhs, (void*)&twihc, (void*)&twihs,
      (void*)&dtab
    };
    hipLaunchCooperativeKernel((const void*)kern_loop, dim3(256), dim3(1024),
                               kargs, 0, stream);
  }

  kern_last<<<dim3(2*C_*16), dim3(256), 0, stream>>>(A1, Z, twi_lut);
}

// Round 18
// 523.126 us; speedup vs baseline: 3.6147x; 3.6147x over previous
//
#include <hip/hip_runtime.h>
#include <hip/hip_fp16.h>
#include <math.h>

#define N_ 4
#define C_ 31
#define H_ 128
#define W_ 128
#define TOTAL (N_*C_*H_*W_)
#define CV_ (C_*H_*W_)
#define PI_F 3.14159265358979f
#define RHO_F 1.05f
#define INV_RHO (1.0f/1.05f)
#define NORM2 (1.0f/16384.0f)    // 1/(128*128)

typedef __attribute__((ext_vector_type(2))) float v2f;
typedef __attribute__((ext_vector_type(2))) _Float16 h2f;

__device__ __forceinline__ v2f cmulv(v2f a, v2f b){
  v2f t = a.x * b;
  v2f s = (v2f){-a.y, a.y};
  return t + s * b.yx;
}
__device__ __forceinline__ v2f shflv(v2f v, int m){
  v2f r; r.x = __shfl_xor(v.x, m, 64); r.y = __shfl_xor(v.y, m, 64); return r;
}
__device__ __forceinline__ h2f shflh(h2f v, int m){
  float f = __builtin_bit_cast(float, v);
  f = __shfl_xor(f, m, 64);
  return __builtin_bit_cast(h2f, f);
}
__device__ __forceinline__ float shrinkf(float x, float t){
  return copysignf(fmaxf(fabsf(x) - t, 0.0f), x);
}
__device__ __forceinline__ uint packh2(v2f v){
  union{__half2 h2; uint u;} cv; cv.h2 = __floats2half2_rn(v.x, v.y); return cv.u;
}
__device__ __forceinline__ v2f unpackh2(uint u){
  union{uint uu; __half2 h2;} cv; cv.uu = u;
  float2 f = __half22float2(cv.h2);
  return (v2f){f.x, f.y};
}
__device__ __forceinline__ v2f h2v(__half2 h){
  float2 f = __half22float2(h);
  return (v2f){f.x, f.y};
}
// V recurrence: vnew = shrink((1+1/rho)*D - vold/rho, thr) + (vold - D)/rho
__device__ __forceinline__ v2f vupd(v2f D, v2f vo, float thr){
  const float aa = 1.0f + INV_RHO;
  return (v2f){
    shrinkf(aa*D.x - vo.x*INV_RHO, thr) + (vo.x - D.x)*INV_RHO,
    shrinkf(aa*D.y - vo.y*INV_RHO, thr) + (vo.y - D.y)*INV_RHO};
}
__device__ __forceinline__ void load_tw(const v2f* __restrict__ lut, v2f* tw, int lane){
  #pragma unroll
  for (int i = 0; i < 7; ++i) tw[i] = lut[i*64 + lane];
}

// Forward DIF FFT-128 (fp32); outputs bit-reversed positions.
__device__ __forceinline__ void fft128_fwd(v2f& a, v2f& b, const v2f* twf, int t){
  v2f u = a + b;
  v2f v = cmulv(a - b, twf[0]);
  #pragma unroll
  for (int i = 1; i < 7; ++i){
    int sp = 64 >> i;
    bool up = (t & sp) != 0;
    v2f pu = shflv(u, sp);
    v2f du = up ? pu - u : u + pu;
    u = cmulv(du, twf[i]);
    v2f pv = shflv(v, sp);
    v2f dv = up ? pv - v : v + pv;
    v = cmulv(dv, twf[i]);
  }
  a = u; b = v;
}

// Inverse DIT FFT-128 (fp32, unnormalized): bit-reversed in, natural out.
__device__ __forceinline__ void fft128_inv(v2f& a, v2f& b, const v2f* twi, int t){
  v2f u = a, v = b;
  #pragma unroll
  for (int i = 6; i >= 1; --i){
    int sp = 64 >> i;
    bool up = (t & sp) != 0;
    v2f pu = shflv(u, sp);
    v2f e  = up ? pu : u;
    v2f o  = up ? u  : pu;
    v2f wo = cmulv(o, twi[i]);
    u = up ? e - wo : e + wo;
    v2f pv = shflv(v, sp);
    v2f ev = up ? pv : v;
    v2f ov = up ? v  : pv;
    v2f wv = cmulv(ov, twi[i]);
    v = up ? ev - wv : ev + wv;
  }
  v2f tv = cmulv(v, twi[0]);
  a = u + tv;
  b = u - tv;
}

// SoA dual-row inverse FFT-128 (fp16 packed): rows P(low), Q(high).
__device__ __forceinline__ void fft128_inv_h2(h2f& are, h2f& aim, h2f& bre, h2f& bim,
    const uint* __restrict__ twc, const uint* __restrict__ tws, int t){
  #pragma unroll
  for (int i = 6; i >= 1; --i){
    int sp = 64 >> i;
    bool up = (t & sp) != 0;
    h2f c2 = __builtin_bit_cast(h2f, twc[i*64 + t]);
    h2f s2 = __builtin_bit_cast(h2f, tws[i*64 + t]);
    h2f pre = shflh(are, sp), pim = shflh(aim, sp);
    h2f e_re = up ? pre : are, e_im = up ? pim : aim;
    h2f o_re = up ? are : pre, o_im = up ? aim : pim;
    are = e_re + (o_re*c2 - o_im*s2);
    aim = e_im + (o_re*s2 + o_im*c2);
    pre = shflh(bre, sp); pim = shflh(bim, sp);
    e_re = up ? pre : bre; e_im = up ? pim : bim;
    o_re = up ? bre : pre; o_im = up ? bim : pim;
    bre = e_re + (o_re*c2 - o_im*s2);
    bim = e_im + (o_re*s2 + o_im*c2);
  }
  h2f c0 = __builtin_bit_cast(h2f, twc[t]);
  h2f s0 = __builtin_bit_cast(h2f, tws[t]);
  h2f tr = bre*c0 - bim*s0;
  h2f ti = bre*s0 + bim*c0;
  h2f ur = are, ui = aim;
  are = ur + tr; aim = ui + ti;
  bre = ur - tr; bim = ui - ti;
}

// SoA dual-row FORWARD DIF FFT-128 (fp16 packed).
__device__ __forceinline__ void fft128_fwd_h2(h2f& are, h2f& aim, h2f& bre, h2f& bim,
    const uint* __restrict__ twc, const uint* __restrict__ tws, int t){
  h2f c0 = __builtin_bit_cast(h2f, twc[t]);
  h2f s0 = __builtin_bit_cast(h2f, tws[t]);
  h2f dre = are - bre, dim = aim - bim;
  h2f ure = are + bre, uim = aim + bim;
  h2f vre = dre*c0 - dim*s0;
  h2f vim = dre*s0 + dim*c0;
  #pragma unroll
  for (int i = 1; i < 7; ++i){
    int sp = 64 >> i;
    bool up = (t & sp) != 0;
    h2f c2 = __builtin_bit_cast(h2f, twc[i*64 + t]);
    h2f s2 = __builtin_bit_cast(h2f, tws[i*64 + t]);
    h2f sg = up ? (h2f){(_Float16)-1.0f, (_Float16)-1.0f} : (h2f){(_Float16)1.0f, (_Float16)1.0f};
    h2f pre = shflh(ure, sp), pim = shflh(uim, sp);
    h2f d1 = sg*ure + pre, d2 = sg*uim + pim;
    ure = d1*c2 - d2*s2; uim = d1*s2 + d2*c2;
    pre = shflh(vre, sp); pim = shflh(vim, sp);
    d1 = sg*vre + pre; d2 = sg*vim + pim;
    vre = d1*c2 - d2*s2; vim = d1*s2 + d2*c2;
  }
  are = ure; aim = uim; bre = vre; bim = vim;
}

// K-1: one-time twiddle/demo LUT init. 1 block, 128 threads.
__global__ __launch_bounds__(128) void kern_init(v2f* __restrict__ twf_lut,
    v2f* __restrict__ twi_lut, float* __restrict__ dtab,
    uint* __restrict__ twihc, uint* __restrict__ twihs,
    uint* __restrict__ twfhc, uint* __restrict__ twfhs)
{
  int t = threadIdx.x;
  if (t < 64){
    float s, c;
    sincosf(-2.0f*PI_F*(float)t/128.0f, &s, &c);
    twf_lut[t] = (v2f){c, s};
    { union{__half2 h; uint u;} cc, ss;
      cc.h = __floats2half2_rn(c, c); ss.h = __floats2half2_rn(s, s);
      twfhc[t] = cc.u; twfhs[t] = ss.u; }
    sincosf(+2.0f*PI_F*(float)t/128.0f, &s, &c);
    twi_lut[t] = (v2f){c, s};
    { union{__half2 h; uint u;} cc, ss;
      cc.h = __floats2half2_rn(c, c); ss.h = __floats2half2_rn(s, s);
      twihc[t] = cc.u; twihs[t] = ss.u; }
    #pragma unroll
    for (int i = 1; i < 7; ++i){
      int sp = 64 >> i;
      float angf = (t & sp) ? -2.0f*PI_F*(float)(t&(sp-1))/(float)(2*sp) : 0.0f;
      sincosf(angf, &s, &c);
      twf_lut[i*64 + t] = (v2f){c, s};
      { union{__half2 h; uint u;} cc, ss;
        cc.h = __floats2half2_rn(c, c); ss.h = __floats2half2_rn(s, s);
        twfhc[i*64 + t] = cc.u; twfhs[i*64 + t] = ss.u; }
      float angi = +2.0f*PI_F*(float)(t&(sp-1))/(float)(2*sp);
      sincosf(angi, &s, &c);
      twi_lut[i*64 + t] = (v2f){c, s};
      float ch = c, sh = s;
      if (t & sp){ ch = -ch; sh = -sh; }
      union{__half2 h; uint u;} cc, ss;
      cc.h = __floats2half2_rn(ch, ch); ss.h = __floats2half2_rn(sh, sh);
      twihc[i*64 + t] = cc.u; twihs[i*64 + t] = ss.u;
    }
  }
  dtab[t] = 2.0f - 2.0f*cosf(2.0f*PI_F*(float)t/128.0f);
}

// K0: one-time pack
__global__ __launch_bounds__(256) void kern_pack(const float* __restrict__ Y,
    const float* __restrict__ W, uint2* __restrict__ YWp)
{
  int i = blockIdx.x * 256 + threadIdx.x;
  int pair = i / CV_, j = i - pair*CV_;
  long b0 = (long)(2*pair)*CV_ + j, b1 = b0 + CV_;
  union{__half2 h2; uint u;} a, b;
  a.h2 = __floats2half2_rn(Y[b0], W[b0]);
  b.h2 = __floats2half2_rn(Y[b1], W[b1]);
  YWp[i] = make_uint2(a.u, b.u);
}

// K1: first iteration.
__global__ __launch_bounds__(256) void kern_fwd0(const float* __restrict__ Y,
    __half2* __restrict__ Vho, __half2* __restrict__ Vvo, __half2* __restrict__ Vso,
    __half2* __restrict__ A, float thr, const v2f* __restrict__ twf_lut)
{
  __shared__ v2f  zbuf[26][128];
  __shared__ uint zs[25][128];
  int tid = threadIdx.x, lane = tid & 63, wv = tid >> 6;
  int b = blockIdx.x;
  int ht = b & 15, c = (b >> 4) % C_, pair = b / (16*C_);
  int h0 = ht * 8;
  int cm1 = c ? c-1 : C_-1, cp1 = (c == C_-1) ? 0 : c+1;
  long v0 = (long)(2*pair)*CV_, v1 = v0 + CV_;

  for (int u = wv; u < 26; u += 4){
    int cc, h;
    if (u < 10){ cc = c; h = (h0 - 1 + u) & (H_-1); }
    else if (u < 18){ cc = cm1; h = h0 + u - 10; }
    else { cc = cp1; h = h0 + u - 18; }
    long rb = ((long)cc*H_ + h)*W_;
    #pragma unroll
    for (int e = 0; e < 2; ++e){
      int w = lane + 64*e;
      zbuf[u][w] = (v2f){Y[v0+rb+w], Y[v1+rb+w]};
    }
  }
  __syncthreads();

  v2f q[2][2], vs[2][2], vsm[2][2];
  #pragma unroll
  for (int r = 0; r < 2; ++r){
    int i = wv + 4*r, h = h0 + i;
    long pv = ((long)(pair*C_ + c)*H_ + h)*W_;
    #pragma unroll
    for (int e = 0; e < 2; ++e){
      int w = lane + 64*e;
      v2f z0 = zbuf[i+1][w];
      v2f zw = zbuf[i+1][(w+1)&(W_-1)];
      v2f zh = zbuf[i+2][w];
      v2f zc = zbuf[18+i][w];
      v2f zm = zbuf[10+i][w];
      v2f vh = (v2f){shrinkf(z0.x-zw.x,thr), shrinkf(z0.y-zw.y,thr)};
      v2f vv = (v2f){shrinkf(z0.x-zh.x,thr), shrinkf(z0.y-zh.y,thr)};
      v2f vsl= (v2f){shrinkf(z0.x-zc.x,thr), shrinkf(z0.y-zc.y,thr)};
      vsm[r][e] = (v2f){shrinkf(zm.x-z0.x,thr), shrinkf(zm.y-z0.y,thr)};
      Vho[pv+w] = __floats2half2_rn(vh.x, vh.y);
      Vvo[pv+w] = __floats2half2_rn(vv.x, vv.y);
      Vso[pv+w] = __floats2half2_rn(vsl.x, vsl.y);
      zs[i][w]   = packh2(vh);
      zs[9+i][w] = packh2(vv);
      vs[r][e] = vsl;
      q[r][e]  = z0;
    }
  }
  if (wv == 0){
    #pragma unroll
    for (int e = 0; e < 2; ++e){
      int w = lane + 64*e;
      v2f z0 = zbuf[0][w], zh = zbuf[1][w];
      v2f vvm = (v2f){shrinkf(z0.x-zh.x,thr), shrinkf(z0.y-zh.y,thr)};
      zs[8][w] = packh2(vvm);
    }
  }
  __syncthreads();

  v2f twf[7]; load_tw(twf_lut, twf, lane);
  #pragma unroll
  for (int r = 0; r < 2; ++r){
    int i = wv + 4*r;
    v2f nm[2];
    #pragma unroll
    for (int e = 0; e < 2; ++e){
      int w = lane + 64*e;
      v2f vh  = unpackh2(zs[i][w]);
      v2f vhm = unpackh2(zs[i][(w+W_-1)&(W_-1)]);
      v2f vv  = unpackh2(zs[9+i][w]);
      v2f vvm = unpackh2(zs[8+i][w]);
      nm[e] = q[r][e] + (vh - vhm) + (vv - vvm) + (vs[r][e] - vsm[r][e]);
    }
    fft128_fwd(nm[0], nm[1], twf, lane);
    zs[17+i][lane]    = packh2(nm[0]);
    zs[17+i][lane+64] = packh2(nm[1]);
  }
  __syncthreads();
  int4* A4 = (int4*)A;
  int p = tid >> 1, hq = tid & 1;
  union{int4 v; uint e[4];} u;
  #pragma unroll
  for (int j = 0; j < 4; ++j) u.e[j] = zs[17 + 4*hq + j][p];
  A4[((long)(pair*W_ + p)*C_ + c)*32 + 2*ht + hq] = u.v;
}

// K2: H-FFT fwd (fp16 SoA) + 17-tap circulant c-solve (fp32) + H-FFT inv (fp16 SoA).
__global__ __launch_bounds__(1024) void kern_CH(__half2* __restrict__ A,
    const uint* __restrict__ twfhc, const uint* __restrict__ twfhs,
    const uint* __restrict__ twihc, const uint* __restrict__ twihs,
    const float* __restrict__ dtab)
{
  __shared__ v2f slab[C_][H_];
  __shared__ v2f slab2[C_][H_];
  int tid = threadIdx.x, lane = tid & 63, wv = tid >> 6;
  int bid = blockIdx.x;                 // pair*128 + w
  int w = bid & (W_-1);
  const int4* g4 = (const int4*)(A + (long)bid * C_ * H_);

  if (tid < 992){
    union { int4 v; __half2 e[4]; } u;
    u.v = g4[tid];
    int c = tid >> 5, hb = (tid & 31) << 2;
    #pragma unroll
    for (int j = 0; j < 4; ++j) slab[c][hb+j] = h2v(u.e[j]);
  }
  __syncthreads();

  {
    int c1 = wv, c2 = (wv + 16 < C_) ? wv + 16 : (C_-1);
    v2f a0 = slab[c1][lane], b0 = slab[c1][lane+64];
    v2f a1 = slab[c2][lane], b1 = slab[c2][lane+64];
    h2f are = (h2f){(_Float16)a0.x, (_Float16)a1.x};
    h2f aim = (h2f){(_Float16)a0.y, (_Float16)a1.y};
    h2f bre = (h2f){(_Float16)b0.x, (_Float16)b1.x};
    h2f bim = (h2f){(_Float16)b0.y, (_Float16)b1.y};
    fft128_fwd_h2(are, aim, bre, bim, twfhc, twfhs, lane);
    slab[c1][lane]    = (v2f){(float)are.x, (float)aim.x};
    slab[c1][lane+64] = (v2f){(float)bre.x, (float)bim.x};
    if (wv + 16 < C_){
      slab[c2][lane]    = (v2f){(float)are.y, (float)aim.y};
      slab[c2][lane+64] = (v2f){(float)bre.y, (float)bim.y};
    }
  }
  __syncthreads();

  {
    int col = tid & (H_-1), cb = tid >> 7, c0 = cb * 4;
    int fh = __brev(col) >> 25;
    int fw = __brev(w)   >> 25;
    float beta = 1.0f + dtab[fh] + dtab[fw];
    float a2 = beta + 2.0f;
    float s  = sqrtf(a2*a2 - 4.0f);
    float rg = (a2 - s) * 0.5f;
    float gt[9];
    gt[0] = NORM2 / s;
    #pragma unroll
    for (int t = 1; t < 9; ++t) gt[t] = gt[t-1] * rg;

    v2f win[20];
    #pragma unroll
    for (int i = 0; i < 20; ++i){
      int ci = c0 - 8 + i;
      if (ci < 0) ci += C_;
      if (ci >= C_) ci -= C_;
      win[i] = slab[ci][col];
    }
    #pragma unroll
    for (int j = 0; j < 4; ++j){
      v2f o = (v2f){0.0f, 0.0f};
      #pragma unroll
      for (int t = -8; t <= 8; ++t){
        float gv = gt[t < 0 ? -t : t];
        o += gv * win[j + 8 - t];
      }
      int c = c0 + j;
      if (c < C_) slab2[c][col] = o;
    }
  }
  __syncthreads();

  {
    int c1 = wv, c2 = (wv + 16 < C_) ? wv + 16 : (C_-1);
    v2f a0 = slab2[c1][lane], b0 = slab2[c1][lane+64];
    v2f a1 = slab2[c2][lane], b1 = slab2[c2][lane+64];
    h2f are = (h2f){(_Float16)a0.x, (_Float16)a1.x};
    h2f aim = (h2f){(_Float16)a0.y, (_Float16)a1.y};
    h2f bre = (h2f){(_Float16)b0.x, (_Float16)b1.x};
    h2f bim = (h2f){(_Float16)b0.y, (_Float16)b1.y};
    fft128_inv_h2(are, aim, bre, bim, twihc, twihs, lane);
    slab2[c1][lane]    = (v2f){(float)are.x, (float)aim.x};
    slab2[c1][lane+64] = (v2f){(float)bre.x, (float)bim.x};
    if (wv + 16 < C_){
      slab2[c2][lane]    = (v2f){(float)are.y, (float)aim.y};
      slab2[c2][lane+64] = (v2f){(float)bre.y, (float)bim.y};
    }
  }
  __syncthreads();
  int4* go4 = (int4*)(A + (long)bid * C_ * H_);
  if (tid < 992){
    int c = tid >> 5, hb = (tid & 31) << 2;
    union { int4 v; __half2 e[4]; } u;
    #pragma unroll
    for (int j = 0; j < 4; ++j){
      v2f f = slab2[c][hb+j];
      u.e[j] = __floats2half2_rn(f.x, f.y);
    }
    go4[tid] = u.v;
  }
}

// K3: fused iteration tail+head, 4c x 8h tiles, 1024 thr = 16 waves, grid 256.
__global__ __launch_bounds__(1024) void kern_CA(
    const __half2* __restrict__ Ain, __half2* __restrict__ Aout,
    const __half2* __restrict__ Vhi, const __half2* __restrict__ Vvi, const __half2* __restrict__ Vsi,
    __half2* __restrict__ Vho, __half2* __restrict__ Vvo, __half2* __restrict__ Vso,
    const uint2* __restrict__ YWp, __half2* __restrict__ G1,
    float mu, float thrn, float invmun, int firstG,
    const uint* __restrict__ twfhc, const uint* __restrict__ twfhs,
    const uint* __restrict__ twihc, const uint* __restrict__ twihs)
{
  __shared__ v2f  zbuf[56][128];   // z rows fp32; later bytes reused as tbuf (uint rows)
  __shared__ uint zs[80][128];     // staging, then Vh/Vv/Vv-halo
  int tid = threadIdx.x, lane = tid & 63, wv = tid >> 6;   // wv 0..15
  int b = blockIdx.x;
  int ht = b & 15, ct = (b >> 4) & 7, pair = b >> 7;
  int c0 = 4*ct, nc = (ct == 7) ? 3 : 4;
  int h0 = ht * 8;
  int k = wv >> 3, hl = wv & 7;
  int cm1 = c0 ? c0-1 : C_-1;
  int cp4 = (c0 + 4) % C_;

  // prefetch own-row global state for cA = c0+2k, cB = (c0+2k+1)%C
  int cA = c0 + 2*k;
  int cB = (c0 + 2*k + 1) % C_;
  int cAm1 = cA ? cA-1 : C_-1;
  int h = h0 + hl;
  long pvA = ((long)(pair*C_ + cA)*H_ + h)*W_;
  long pvB = ((long)(pair*C_ + cB)*H_ + h)*W_;
  long pvM = ((long)(pair*C_ + cAm1)*H_ + h)*W_;
  uint pf_vh[2][2], pf_vv[2][2], pf_vs[2][2], pf_vsmA[2], pf_g1[2][2], pf_vvh[2];
  uint2 pf_yw[2][2];
  #pragma unroll
  for (int e = 0; e < 2; ++e){
    int w = lane + 64*e;
    pf_vh[0][e] = *(const uint*)(Vhi + pvA + w);
    pf_vh[1][e] = *(const uint*)(Vhi + pvB + w);
    pf_vv[0][e] = *(const uint*)(Vvi + pvA + w);
    pf_vv[1][e] = *(const uint*)(Vvi + pvB + w);
    pf_vs[0][e] = *(const uint*)(Vsi + pvA + w);
    pf_vs[1][e] = *(const uint*)(Vsi + pvB + w);
    pf_vsmA[e]  = *(const uint*)(Vsi + pvM + w);
    pf_yw[0][e] = YWp[pvA + w];
    pf_yw[1][e] = YWp[pvB + w];
    pf_g1[0][e] = *(const uint*)(G1 + pvA + w);
    pf_g1[1][e] = *(const uint*)(G1 + pvB + w);
  }
  if (wv < 4){
    int cc = (c0 + wv) % C_;
    long pvh = ((long)(pair*C_ + cc)*H_ + ((h0+H_-1)&(H_-1)))*W_;
    #pragma unroll
    for (int e = 0; e < 2; ++e){
      int w = lane + 64*e;
      pf_vvh[e] = *(const uint*)(Vvi + pvh + w);
    }
  }

  // phase 0: stage 20 quads (16 own-window + 4 c-halo) = 2560 int4.
  const int4* A4 = (const int4*)Ain;
  #pragma unroll
  for (int kk = 0; kk < 3; ++kk){
    int s = tid + 1024*kk;
    if (s < 2560){
      int qq = s >> 7, w = s & 127;
      int cc, hq, base;
      if (qq < 16){
        cc = (c0 + (qq >> 2)) % C_;
        hq = (2*ht - 1 + (qq & 3)) & 31;
        base = (qq >> 2)*16 + (qq & 3)*4;
      } else if (qq < 18){
        cc = cm1; hq = 2*ht + (qq - 16); base = 64 + (qq - 16)*4;
      } else {
        cc = cp4; hq = 2*ht + (qq - 18); base = 72 + (qq - 18)*4;
      }
      union{int4 v; uint e[4];} u;
      u.v = A4[((long)(pair*W_ + w)*C_ + cc)*32 + hq];
      #pragma unroll
      for (int j = 0; j < 4; ++j) zs[base+j][w] = u.e[j];
    }
  }
  __syncthreads();

  // phase 1: iFFT 56 zbuf rows = 28 SoA units; wave does unit wv and (wv<12) 16+wv.
  {
    #pragma unroll
    for (int kk = 0; kk < 2; ++kk){
      int j = wv + 16*kk;
      if (kk == 1 && j >= 28) break;
      int bP = 2*j, bQ = 2*j + 1;
      int zrP = (bP < 40) ? ((bP/10)*16 + (bP%10) + 3) : (bP + 24);
      int zrQ = (bQ < 40) ? ((bQ/10)*16 + (bQ%10) + 3) : (bQ + 24);
      uint r0a = zs[zrP][lane],    r1a = zs[zrQ][lane];
      uint r0b = zs[zrP][lane+64], r1b = zs[zrQ][lane+64];
      h2f are = __builtin_bit_cast(h2f, (r0a & 0xffffu) | (r1a << 16));
      h2f aim = __builtin_bit_cast(h2f, (r0a >> 16) | (r1a & 0xffff0000u));
      h2f bre = __builtin_bit_cast(h2f, (r0b & 0xffffu) | (r1b << 16));
      h2f bim = __builtin_bit_cast(h2f, (r0b >> 16) | (r1b & 0xffff0000u));
      fft128_inv_h2(are, aim, bre, bim, twihc, twihs, lane);
      zbuf[bP][lane]    = (v2f){(float)are.x, (float)aim.x};
      zbuf[bP][lane+64] = (v2f){(float)bre.x, (float)bim.x};
      zbuf[bQ][lane]    = (v2f){(float)are.y, (float)aim.y};
      zbuf[bQ][lane+64] = (v2f){(float)bre.y, (float)bim.y};
    }
  }
  __syncthreads();

  // phase 2a: V_{t+1} for rows (cA,hl),(cB,hl); X/G1/Q.
  v2f q2[2][2], vs2[2][2], vsm2[2][2];
  #pragma unroll
  for (int s = 0; s < 2; ++s){
    int cL = 2*k + s;
    bool valid = (cL < nc);
    int zb0 = 10*cL + 1 + hl;
    int zbc = (cL < 3) ? (10*(cL+1) + 1 + hl) : (48 + hl);
    int zbm = (cL == 0) ? (40 + hl) : (10*(cL-1) + 1 + hl);
    long pv = (s == 0) ? pvA : pvB;
    #pragma unroll
    for (int e = 0; e < 2; ++e){
      int w = lane + 64*e;
      v2f z0 = zbuf[zb0][w];
      v2f zw = zbuf[zb0][(w+1)&(W_-1)];
      v2f zh = zbuf[zb0+1][w];
      v2f zc = zbuf[zbc][w];
      v2f vh  = vupd(z0 - zw, unpackh2(pf_vh[s][e]), thrn);
      v2f vv  = vupd(z0 - zh, unpackh2(pf_vv[s][e]), thrn);
      v2f vsl = vupd(z0 - zc, unpackh2(pf_vs[s][e]), thrn);
      if (s == 0){
        v2f zm = zbuf[zbm][w];
        vsm2[0][e] = vupd(zm - z0, unpackh2(pf_vsmA[e]), thrn);
        vsm2[1][e] = vsl;     // cB's (c-1) term = cA's Vs
      }
      if (valid){
        Vho[pv+w] = __floats2half2_rn(vh.x, vh.y);
        Vvo[pv+w] = __floats2half2_rn(vv.x, vv.y);
        Vso[pv+w] = __floats2half2_rn(vsl.x, vsl.y);
      }
      zs[cL*8 + hl][w]      = packh2(vh);
      zs[32 + cL*8 + hl][w] = packh2(vv);
      vs2[s][e] = vsl;
      v2f a0 = unpackh2(pf_yw[s][e].x);
      v2f a1 = unpackh2(pf_yw[s][e].y);
      v2f g1 = firstG ? (v2f){0.0f, 0.0f} : unpackh2(pf_g1[s][e]);
      float x0 = (a0.y*a0.x + mu*z0.x - g1.x) * __builtin_amdgcn_rcpf(a0.y + mu);
      float x1 = (a1.y*a1.x + mu*z0.y - g1.y) * __builtin_amdgcn_rcpf(a1.y + mu);
      float g10 = g1.x + mu*(x0 - z0.x);
      float g11 = g1.y + mu*(x1 - z0.y);
      if (valid) G1[pv+w] = __floats2half2_rn(g10, g11);
      q2[s][e] = (v2f){x0 + g10*invmun, x1 + g11*invmun};
    }
  }
  if (wv < 4){
    int zb = 10*wv;               // z(c0+wv, h0-1)
    #pragma unroll
    for (int e = 0; e < 2; ++e){
      int w = lane + 64*e;
      v2f z0 = zbuf[zb][w], zh = zbuf[zb+1][w];
      v2f vvm = vupd(z0 - zh, unpackh2(pf_vvh[e]), thrn);
      zs[64 + wv][w] = packh2(vvm);
    }
  }
  __syncthreads();

  // phase 2b: numer + forward W-FFT (2 rows as one fp16-SoA FFT); tbuf aliases zbuf.
  {
    v2f nm[2][2];
    #pragma unroll
    for (int s = 0; s < 2; ++s){
      int cL = 2*k + s;
      #pragma unroll
      for (int e = 0; e < 2; ++e){
        int w = lane + 64*e;
        v2f vh  = unpackh2(zs[cL*8 + hl][w]);
        v2f vhm = unpackh2(zs[cL*8 + hl][(w+W_-1)&(W_-1)]);
        v2f vv  = unpackh2(zs[32 + cL*8 + hl][w]);
        v2f vvm = (hl == 0) ? unpackh2(zs[64 + cL][w]) : unpackh2(zs[32 + cL*8 + hl - 1][w]);
        nm[s][e] = q2[s][e] + (vh - vhm) + (vv - vvm) + (vs2[s][e] - vsm2[s][e]);
      }
    }
    bool validB = (2*k + 1 < nc);
    if (!validB){ nm[1][0] = nm[0][0]; nm[1][1] = nm[0][1]; }
    h2f are = (h2f){(_Float16)nm[0][0].x, (_Float16)nm[1][0].x};
    h2f aim = (h2f){(_Float16)nm[0][0].y, (_Float16)nm[1][0].y};
    h2f bre = (h2f){(_Float16)nm[0][1].x, (_Float16)nm[1][1].x};
    h2f bim = (h2f){(_Float16)nm[0][1].y, (_Float16)nm[1][1].y};
    fft128_fwd_h2(are, aim, bre, bim, twfhc, twfhs, lane);
    uint a_ = __builtin_bit_cast(uint, are), ai_ = __builtin_bit_cast(uint, aim);
    uint b_ = __builtin_bit_cast(uint, bre), bi_ = __builtin_bit_cast(uint, bim);
    uint* tb = (uint*)zbuf;
    int r0 = (2*k)*8 + hl, r1 = (2*k+1)*8 + hl;
    tb[r0*128 + lane]      = (a_ & 0xffffu) | (ai_ << 16);
    tb[r0*128 + lane + 64] = (b_ & 0xffffu) | (bi_ << 16);
    if (validB){
      tb[r1*128 + lane]      = (a_ >> 16) | (ai_ & 0xffff0000u);
      tb[r1*128 + lane + 64] = (b_ >> 16) | (bi_ & 0xffff0000u);
    }
  }
  __syncthreads();

  // phase 3: store 8 own quads (4c x 2 quads) = 1024 int4, one per thread.
  {
    int q = tid >> 7, w = tid & 127;
    int cL = q >> 1, hq2 = q & 1;
    if (cL < nc){
      const uint* tb = (const uint*)zbuf;
      int4* Ao4 = (int4*)Aout;
      union{int4 v; uint e[4];} uo;
      #pragma unroll
      for (int j = 0; j < 4; ++j) uo.e[j] = tb[(cL*8 + 4*hq2 + j)*128 + w];
      Ao4[((long)(pair*W_ + w)*C_ + (c0+cL))*32 + 2*ht + hq2] = uo.v;
    }
  }
}

// K4: final: iW-FFT own rows only -> Z fp32.
__global__ __launch_bounds__(256) void kern_last(const __half2* __restrict__ A,
    float* __restrict__ Z, const v2f* __restrict__ twi_lut)
{
  __shared__ uint zs[8][128];
  int tid = threadIdx.x, lane = tid & 63, wv = tid >> 6;
  int b = blockIdx.x;
  int ht = b & 15, c = (b >> 4) % C_, pair = b / (16*C_);
  int h0 = ht * 8;
  const int4* A4 = (const int4*)A;
  {
    int p = tid >> 1, hq = tid & 1;
    union{int4 v; uint e[4];} u;
    u.v = A4[((long)(pair*W_ + p)*C_ + c)*32 + 2*ht + hq];
    #pragma unroll
    for (int j = 0; j < 4; ++j) zs[4*hq + j][p] = u.e[j];
  }
  __syncthreads();
  v2f twi[7]; load_tw(twi_lut, twi, lane);
  long v0 = (long)(2*pair)*CV_, v1 = v0 + CV_;
  #pragma unroll
  for (int r = 0; r < 2; ++r){
    int i = wv + 4*r, h = h0 + i;
    v2f a = unpackh2(zs[i][lane]);
    v2f bb = unpackh2(zs[i][lane+64]);
    fft128_inv(a, bb, twi, lane);
    long rb = ((long)c*H_ + h)*W_;
    Z[v0+rb+lane]    = a.x;  Z[v1+rb+lane]    = a.y;
    Z[v0+rb+lane+64] = bb.x; Z[v1+rb+lane+64] = bb.y;
  }
}

extern "C" void kernel_launch(void* const* d_in, const int* in_sizes, int n_in,
                              void* d_out, int out_size, void* d_ws, size_t ws_size,
                              hipStream_t stream)
{
  const float* Y   = (const float*)d_in[0];
  const float* inW = (const float*)d_in[1];
  float* Z = (float*)d_out;

  v2f*   twf_lut = (v2f*)d_ws;
  v2f*   twi_lut = twf_lut + 7*64;
  float* dtab    = (float*)(twi_lut + 7*64);
  uint*  twihc   = (uint*)(dtab + 128);
  uint*  twihs   = twihc + 7*64;
  uint*  twfhc   = twihs + 7*64;
  uint*  twfhs   = twfhc + 7*64;
  char*  fields  = (char*)d_ws + 16384;

  const int HT = TOTAL/2;
  uint2*   YWp = (uint2*)fields;
  __half2* G1  = (__half2*)(YWp + HT);
  __half2* Vh0 = G1  + HT;
  __half2* Vv0 = Vh0 + HT;
  __half2* Vs0 = Vv0 + HT;
  __half2* Vh1 = Vs0 + HT;
  __half2* Vv1 = Vh1 + HT;
  __half2* Vs1 = Vv1 + HT;
  __half2* A0  = Vs1 + HT;
  __half2* A1  = A0  + HT;
  __half2* Vh[2] = {Vh0, Vh1};
  __half2* Vv[2] = {Vv0, Vv1};
  __half2* Vs[2] = {Vs0, Vs1};
  __half2* Ab[2] = {A0, A1};

  kern_init<<<dim3(1), dim3(128), 0, stream>>>(twf_lut, twi_lut, dtab, twihc, twihs, twfhc, twfhs);
  kern_pack<<<dim3(2*CV_/256), dim3(256), 0, stream>>>(Y, inW, YWp);
  kern_fwd0<<<dim3(2*C_*16), dim3(256), 0, stream>>>(Y, Vh0, Vv0, Vs0, A0, 1.0f, twf_lut);

  float mu = 0.1f;
  for (int t = 0; t < 19; ++t){
    kern_CH<<<dim3(2*W_), dim3(1024), 0, stream>>>(Ab[t&1], twfhc, twfhs, twihc, twihs, dtab);
    float mun = mu * RHO_F;
    kern_CA<<<dim3(256), dim3(1024), 0, stream>>>(
        Ab[t&1], Ab[(t+1)&1],
        Vh[t&1], Vv[t&1], Vs[t&1],
        Vh[(t+1)&1], Vv[(t+1)&1], Vs[(t+1)&1],
        YWp, G1, mu, 0.1f/mun, 1.0f/mun, (t==0) ? 1 : 0,
        twfhc, twfhs, twihc, twihs);
    mu = mun;
  }
  kern_CH<<<dim3(2*W_), dim3(1024), 0, stream>>>(Ab[1], twfhc, twfhs, twihc, twihs, dtab);
  kern_last<<<dim3(2*C_*16), dim3(256), 0, stream>>>(Ab[1], Z, twi_lut);
}